// Round 3
// baseline (97.190 us; speedup 1.0000x reference)
//
#include <hip/hip_runtime.h>

#define T_TOK 65536
#define DDIM 512
#define NEXP 8
#define CAP 16384
#define PADX 132  // 128 + 4 pad: stride 132 floats = 528B = 33*16B (aligned), conflict-free b128

__device__ inline float wave_sum(float v) {
#pragma unroll
  for (int m = 1; m < 64; m <<= 1) v += __shfl_xor(v, m, 64);
  return v;
}

// --- K0a: w2s[e*H+h] = sum_d W2[e,h,d]; one wave per row, 4096 rows ---
__global__ void k_w2s(const float* __restrict__ W2, float* __restrict__ w2s) {
  int w = threadIdx.x >> 6, lane = threadIdx.x & 63;
  int row = blockIdx.x * 4 + w;  // < 4096
  const float* p = W2 + (size_t)row * 512;
  float sum = 0.f;
#pragma unroll
  for (int j = 0; j < 8; ++j) sum += p[lane + j * 64];
  sum = wave_sum(sum);
  if (lane == 0) w2s[row] = sum;
}

// --- K0b: vT[d*8+e] = sum_h W1[e,d,h]*w2s[e,h]; last block computes beta[e] ---
__global__ void k_v_beta(const float* __restrict__ W1, const float* __restrict__ b1,
                         const float* __restrict__ b2, const float* __restrict__ w2s,
                         float* __restrict__ vT, float* __restrict__ beta) {
  int w = threadIdx.x >> 6, lane = threadIdx.x & 63;
  if (blockIdx.x < 1024) {
    int rid = blockIdx.x * 4 + w;  // rid = e*512 + d
    int e = rid >> 9, d = rid & 511;
    const float* p = W1 + (size_t)rid * 512;
    const float* q = w2s + e * 512;
    float sum = 0.f;
#pragma unroll
    for (int j = 0; j < 8; ++j) { int h = lane + j * 64; sum += p[h] * q[h]; }
    sum = wave_sum(sum);
    if (lane == 0) vT[d * 8 + e] = sum;
  } else {
    // beta[e] = sum_h b1[e,h]*w2s[e,h] + sum_d b2[e,d]
#pragma unroll
    for (int r = 0; r < 2; ++r) {
      int e = w + r * 4;
      float sum = 0.f;
#pragma unroll
      for (int j = 0; j < 8; ++j) {
        int i = lane + j * 64;
        sum += b1[e * 512 + i] * w2s[e * 512 + i] + b2[e * 512 + i];
      }
      sum = wave_sum(sum);
      if (lane == 0) beta[e] = sum;
    }
  }
}

// --- K1: per token 16 dots: [0..7]=x·Wg (logits), [8..15]=x·v. 64 tokens/block,
// token-per-lane; wave w owns 4 of the 16 outputs (uniform weight loads -> s_load).
// Register double-buffer: prefetch chunk c+1 into regs while computing chunk c,
// so the vmcnt drain lands after the compute phase (T14 async-stage split).
__global__ __launch_bounds__(256, 4) void k_dots(const float* __restrict__ x,
                                                 const float* __restrict__ Wg,
                                                 const float* __restrict__ vT,
                                                 float* __restrict__ dots) {
  __shared__ float sX[64 * PADX];  // 33792 B -> 4 blocks/CU
  int tid = threadIdx.x;
  int lane = tid & 63;
  int wu = __builtin_amdgcn_readfirstlane(tid >> 6);  // force SGPR -> scalar loads
  const float* Pq = (wu < 2) ? Wg : vT;               // both laid out [d][8]
  int qb = (wu & 1) * 4;
  int t0 = blockIdx.x * 64;

  // staging address (fixed per thread): token row + float4 slot within 128-dim chunk
  int f   = tid;                 // plus r*256
  float4 stg[8];
  const float* xbase = x + (size_t)t0 * 512;

  // prologue: prefetch chunk 0
#pragma unroll
  for (int r = 0; r < 8; ++r) {
    int ff = f + r * 256;
    int tok = ff >> 5;
    int dl = (ff & 31) * 4;
    stg[r] = *reinterpret_cast<const float4*>(xbase + (size_t)tok * 512 + dl);
  }

  float a0 = 0.f, a1 = 0.f, a2 = 0.f, a3 = 0.f;
  for (int c = 0; c < 4; ++c) {  // 4 chunks of 128 dims
    if (c) __syncthreads();      // all waves done reading LDS before overwrite
    // store prefetched chunk c into LDS
#pragma unroll
    for (int r = 0; r < 8; ++r) {
      int ff = f + r * 256;
      int tok = ff >> 5;
      int dl = (ff & 31) * 4;
      *reinterpret_cast<float4*>(&sX[tok * PADX + dl]) = stg[r];
    }
    __syncthreads();
    // issue prefetch of chunk c+1 (consumed next iteration, after compute)
    if (c < 3) {
#pragma unroll
      for (int r = 0; r < 8; ++r) {
        int ff = f + r * 256;
        int tok = ff >> 5;
        int dl = (ff & 31) * 4;
        stg[r] = *reinterpret_cast<const float4*>(xbase + (size_t)tok * 512 + (c + 1) * 128 + dl);
      }
    }
    // compute chunk c
    const float* xrow = &sX[lane * PADX];
#pragma unroll 8
    for (int dd = 0; dd < 128; dd += 4) {
      float4 xv = *reinterpret_cast<const float4*>(xrow + dd);
      int dg = c * 128 + dd;
      float4 u0 = *reinterpret_cast<const float4*>(Pq + (size_t)(dg + 0) * 8 + qb);
      float4 u1 = *reinterpret_cast<const float4*>(Pq + (size_t)(dg + 1) * 8 + qb);
      float4 u2 = *reinterpret_cast<const float4*>(Pq + (size_t)(dg + 2) * 8 + qb);
      float4 u3 = *reinterpret_cast<const float4*>(Pq + (size_t)(dg + 3) * 8 + qb);
      a0 += xv.x * u0.x + xv.y * u1.x + xv.z * u2.x + xv.w * u3.x;
      a1 += xv.x * u0.y + xv.y * u1.y + xv.z * u2.y + xv.w * u3.y;
      a2 += xv.x * u0.z + xv.y * u1.z + xv.z * u2.z + xv.w * u3.z;
      a3 += xv.x * u0.w + xv.y * u1.w + xv.z * u2.w + xv.w * u3.w;
    }
  }
  float4 o; o.x = a0; o.y = a1; o.z = a2; o.w = a3;
  *reinterpret_cast<float4*>(dots + (size_t)(t0 + lane) * 16 + wu * 4) = o;
}

// --- K2a: top-2 select + renorm weights + per-block expert histograms ---
__global__ void k_top2(const float* __restrict__ dots, const float* __restrict__ beta,
                       float4* __restrict__ wd, int* __restrict__ epk,
                       int* __restrict__ hist) {
  __shared__ int c0[8], c1[8];
  int tid = threadIdx.x;
  if (tid < 8) { c0[tid] = 0; c1[tid] = 0; }
  __syncthreads();
  int t = blockIdx.x * 256 + tid;
  const float* p = dots + (size_t)t * 16;
  float l[8], dv[8];
#pragma unroll
  for (int e = 0; e < 8; ++e) { l[e] = p[e]; dv[e] = p[8 + e]; }
  int e1 = 0; float v1 = l[0];
#pragma unroll
  for (int e = 1; e < 8; ++e) if (l[e] > v1) { v1 = l[e]; e1 = e; }  // ties -> low idx
  int e2 = 0; float v2 = -3.4e38f;
#pragma unroll
  for (int e = 0; e < 8; ++e) if (e != e1 && l[e] > v2) { v2 = l[e]; e2 = e; }
  float wexp = expf(v2 - v1);           // g2/g1 after softmax; renorm over top-2
  float w1 = 1.f / (1.f + wexp);
  float w2 = wexp * w1;
  float d1 = 0.f, d2 = 0.f;
#pragma unroll
  for (int e = 0; e < 8; ++e) {
    d1 = (e == e1) ? dv[e] : d1;
    d2 = (e == e2) ? dv[e] : d2;
  }
  float4 o; o.x = w1; o.y = w2; o.z = d1 + beta[e1]; o.w = d2 + beta[e2];
  wd[t] = o;
  epk[t] = e1 | (e2 << 8);
  atomicAdd(&c0[e1], 1);
  atomicAdd(&c1[e2], 1);
  __syncthreads();
  if (tid < 8) {
    hist[blockIdx.x * 8 + tid] = c0[tid];
    hist[(256 + blockIdx.x) * 8 + tid] = c1[tid];
  }
}

// --- K2b: exclusive scan of 512 block-histograms (k-major order), per expert ---
__global__ void k_scan(const int* __restrict__ hist, int* __restrict__ off) {
  __shared__ int sH[4096];
  __shared__ int sT[256];
  int tid = threadIdx.x;
  for (int i = tid; i < 4096; i += 256) sH[i] = hist[i];
  __syncthreads();
  int e = tid & 7, g = tid >> 3;  // g < 32, each scans 16 rows
  int run = 0;
  for (int i = g * 16; i < g * 16 + 16; ++i) {
    int cv = sH[i * 8 + e]; sH[i * 8 + e] = run; run += cv;
  }
  sT[g * 8 + e] = run;
  __syncthreads();
  if (tid < 8) {
    int run2 = 0;
    for (int g2 = 0; g2 < 32; ++g2) {
      int cv = sT[g2 * 8 + tid]; sT[g2 * 8 + tid] = run2; run2 += cv;
    }
  }
  __syncthreads();
  int add = sT[g * 8 + e];
  for (int i = g * 16; i < g * 16 + 16; ++i) sH[i * 8 + e] += add;
  __syncthreads();
  for (int i = tid; i < 4096; i += 256) off[i] = sH[i];
}

// --- K2c: stable intra-block ranks via ballots -> pos -> keep -> s[t] ---
__global__ void k_keep(const int* __restrict__ epk, const float4* __restrict__ wd,
                       const int* __restrict__ off, float* __restrict__ s) {
  __shared__ int sC0[32], sC1[32];
  int tid = threadIdx.x, lane = tid & 63, w = tid >> 6;
  int t = blockIdx.x * 256 + tid;
  int ep = epk[t]; int e1 = ep & 255, e2 = ep >> 8;
  unsigned long long lt = (1ull << lane) - 1ull;
  int wr0 = 0, wr1 = 0;
#pragma unroll
  for (int e = 0; e < 8; ++e) {
    unsigned long long m0 = __ballot(e1 == e);
    unsigned long long m1 = __ballot(e2 == e);
    if (e == e1) wr0 = __popcll(m0 & lt);
    if (e == e2) wr1 = __popcll(m1 & lt);
    if (lane == 0) { sC0[w * 8 + e] = __popcll(m0); sC1[w * 8 + e] = __popcll(m1); }
  }
  __syncthreads();
  int woff0 = 0, woff1 = 0;
  for (int wp = 0; wp < 4; ++wp) {
    if (wp < w) { woff0 += sC0[wp * 8 + e1]; woff1 += sC1[wp * 8 + e2]; }
  }
  int b = blockIdx.x;
  int pos0 = off[b * 8 + e1] + woff0 + wr0;
  int pos1 = off[(256 + b) * 8 + e2] + woff1 + wr1;
  float4 v = wd[t];
  float sv = 0.f;
  if (pos0 < CAP) sv += v.x * v.z;
  if (pos1 < CAP) sv += v.y * v.w;
  s[t] = sv;
}

// --- K3: per-row (B=8 rows of N=8192) log_softmax ---
__global__ __launch_bounds__(1024) void k_lsm(const float* __restrict__ s,
                                              float* __restrict__ out) {
  __shared__ float sRa[16], sRb[16];
  int tid = threadIdx.x, lane = tid & 63, w = tid >> 6;
  size_t base = (size_t)blockIdx.x * 8192;
  float v[8];
#pragma unroll
  for (int j = 0; j < 8; ++j) v[j] = s[base + tid + j * 1024];
  float mx = v[0];
#pragma unroll
  for (int j = 1; j < 8; ++j) mx = fmaxf(mx, v[j]);
#pragma unroll
  for (int m = 1; m < 64; m <<= 1) mx = fmaxf(mx, __shfl_xor(mx, m, 64));
  if (lane == 0) sRa[w] = mx;
  __syncthreads();
#pragma unroll
  for (int i = 0; i < 16; ++i) mx = fmaxf(mx, sRa[i]);
  float sum = 0.f;
#pragma unroll
  for (int j = 0; j < 8; ++j) sum += expf(v[j] - mx);
#pragma unroll
  for (int m = 1; m < 64; m <<= 1) sum += __shfl_xor(sum, m, 64);
  if (lane == 0) sRb[w] = sum;
  __syncthreads();
  float tot = 0.f;
#pragma unroll
  for (int i = 0; i < 16; ++i) tot += sRb[i];
  float lse = logf(tot);
#pragma unroll
  for (int j = 0; j < 8; ++j) out[base + tid + j * 1024] = v[j] - mx - lse;
}

extern "C" void kernel_launch(void* const* d_in, const int* in_sizes, int n_in,
                              void* d_out, int out_size, void* d_ws, size_t ws_size,
                              hipStream_t stream) {
  const float* x  = (const float*)d_in[0];
  const float* Wg = (const float*)d_in[1];
  const float* W1 = (const float*)d_in[2];
  const float* b1 = (const float*)d_in[3];
  const float* W2 = (const float*)d_in[4];
  const float* b2 = (const float*)d_in[5];
  float* out = (float*)d_out;
  char* ws = (char*)d_ws;

  float*  w2s  = (float*)(ws);                          // 16 KB
  float*  vT   = (float*)(ws + (16u << 10));            // 16 KB
  float*  beta = (float*)(ws + (32u << 10));            // 32 B (padded)
  float*  dots = (float*)(ws + (64u << 10));            // 4 MB
  char*   p1   = ws + (64u << 10) + (4u << 20);
  float4* wd   = (float4*)(p1);                         // 1 MB
  int*    epk  = (int*)(p1 + (1u << 20));               // 256 KB
  int*    hist = (int*)(p1 + (1u << 20) + (256u << 10));// 16 KB
  int*    offa = (int*)(p1 + (1u << 20) + (272u << 10));// 16 KB
  float*  s    = (float*)(p1 + (1u << 20) + (288u << 10)); // 256 KB

  hipLaunchKernelGGL(k_w2s,    dim3(1024), dim3(256),  0, stream, W2, w2s);
  hipLaunchKernelGGL(k_v_beta, dim3(1025), dim3(256),  0, stream, W1, b1, b2, w2s, vT, beta);
  hipLaunchKernelGGL(k_dots,   dim3(1024), dim3(256),  0, stream, x, Wg, vT, dots);
  hipLaunchKernelGGL(k_top2,   dim3(256),  dim3(256),  0, stream, dots, beta, wd, epk, hist);
  hipLaunchKernelGGL(k_scan,   dim3(1),    dim3(256),  0, stream, hist, offa);
  hipLaunchKernelGGL(k_keep,   dim3(256),  dim3(256),  0, stream, epk, wd, offa, s);
  hipLaunchKernelGGL(k_lsm,    dim3(8),    dim3(1024), 0, stream, s, out);
}

// Round 4
// 85.820 us; speedup vs baseline: 1.1325x; 1.1325x over previous
//
#include <hip/hip_runtime.h>

#define T_TOK 65536
#define DDIM 512
#define NEXP 8
#define CAP 16384

__device__ inline float wave_sum(float v) {
#pragma unroll
  for (int m = 1; m < 64; m <<= 1) v += __shfl_xor(v, m, 64);
  return v;
}

__device__ __forceinline__ void async_cp16(const float* g, void* l) {
  __builtin_amdgcn_global_load_lds(
      (const __attribute__((address_space(1))) void*)g,
      (__attribute__((address_space(3))) void*)l, 16, 0, 0);
}

// --- K0a: w2s[e*H+h] = sum_d W2[e,h,d]; one wave per row, 4096 rows ---
__global__ void k_w2s(const float* __restrict__ W2, float* __restrict__ w2s) {
  int w = threadIdx.x >> 6, lane = threadIdx.x & 63;
  int row = blockIdx.x * 4 + w;  // < 4096
  const float* p = W2 + (size_t)row * 512;
  float sum = 0.f;
#pragma unroll
  for (int j = 0; j < 8; ++j) sum += p[lane + j * 64];
  sum = wave_sum(sum);
  if (lane == 0) w2s[row] = sum;
}

// --- K0b: vT[d*8+e] = sum_h W1[e,d,h]*w2s[e,h]; last block computes beta[e] ---
__global__ void k_v_beta(const float* __restrict__ W1, const float* __restrict__ b1,
                         const float* __restrict__ b2, const float* __restrict__ w2s,
                         float* __restrict__ vT, float* __restrict__ beta) {
  int w = threadIdx.x >> 6, lane = threadIdx.x & 63;
  if (blockIdx.x < 1024) {
    int rid = blockIdx.x * 4 + w;  // rid = e*512 + d
    int e = rid >> 9, d = rid & 511;
    const float* p = W1 + (size_t)rid * 512;
    const float* q = w2s + e * 512;
    float sum = 0.f;
#pragma unroll
    for (int j = 0; j < 8; ++j) { int h = lane + j * 64; sum += p[h] * q[h]; }
    sum = wave_sum(sum);
    if (lane == 0) vT[d * 8 + e] = sum;
  } else {
    // beta[e] = sum_h b1[e,h]*w2s[e,h] + sum_d b2[e,d]
#pragma unroll
    for (int r = 0; r < 2; ++r) {
      int e = w + r * 4;
      float sum = 0.f;
#pragma unroll
      for (int j = 0; j < 8; ++j) {
        int i = lane + j * 64;
        sum += b1[e * 512 + i] * w2s[e * 512 + i] + b2[e * 512 + i];
      }
      sum = wave_sum(sum);
      if (lane == 0) beta[e] = sum;
    }
  }
}

// --- K1: per token 16 dots: [0..7]=x·Wg (logits), [8..15]=x·v.
// 64 tokens/block, token-per-lane; wave wu owns 4 of the 16 outputs
// (wave-uniform weight loads -> s_load). Staging via global_load_lds DMA,
// double-buffered LDS, 8 phases of 64 dims. XOR swizzle p = j ^ (t&15)
// applied on BOTH sides (pre-swizzled global source addr; swizzled ds_read)
// so the DMA's linear lane-order dest is correct and reads are conflict-free.
__global__ __launch_bounds__(256, 2) void k_dots(const float* __restrict__ x,
                                                 const float* __restrict__ Wg,
                                                 const float* __restrict__ vT,
                                                 float* __restrict__ dots) {
  __shared__ float4 sX[2][1024];  // 2 x 16 KB
  int tid = threadIdx.x;
  int lane = tid & 63;
  int wu = __builtin_amdgcn_readfirstlane(tid >> 6);
  const float* Pq = (wu < 2) ? Wg : vT;  // both laid out [d][8]
  int qb = (wu & 1) * 4;
  int t0 = blockIdx.x * 64;
  const float* xbase = x + (size_t)t0 * 512;

  // Stage geometry: call k of wave wu covers float4-slots [(wu*4+k)*64, +64),
  // lane i -> slot s = (wu*4+k)*64 + i; token t = s>>4 = 16*wu + 4*k + (i>>4);
  // physical p = i&15 holds logical float4 j = p ^ (t&15), t&15 = 4k + (i>>4).
  // Per-lane global source (floats): t*512 + 4*j  (+ c*64 per phase).
  int i4 = lane >> 4, p15 = lane & 15;
  const float* g0 = xbase + (size_t)(16 * wu + 4 * 0 + i4) * 512 + 4 * (p15 ^ (4 * 0 + i4));
  const float* g1 = xbase + (size_t)(16 * wu + 4 * 1 + i4) * 512 + 4 * (p15 ^ (4 * 1 + i4));
  const float* g2 = xbase + (size_t)(16 * wu + 4 * 2 + i4) * 512 + 4 * (p15 ^ (4 * 2 + i4));
  const float* g3 = xbase + (size_t)(16 * wu + 4 * 3 + i4) * 512 + 4 * (p15 ^ (4 * 3 + i4));

  float a0 = 0.f, a1 = 0.f, a2 = 0.f, a3 = 0.f;

  // prologue: stage phase 0 into buf 0
  async_cp16(g0, &sX[0][(wu * 4 + 0) * 64]);
  async_cp16(g1, &sX[0][(wu * 4 + 1) * 64]);
  async_cp16(g2, &sX[0][(wu * 4 + 2) * 64]);
  async_cp16(g3, &sX[0][(wu * 4 + 3) * 64]);
  __syncthreads();  // vmcnt(0) drain + barrier: buf0 ready

  int buf = 0;
  for (int c = 0; c < 8; ++c) {
    if (c < 7) {  // stage next phase into other buffer (drained at the barrier below)
      int nb = buf ^ 1, co = (c + 1) * 64;
      async_cp16(g0 + co, &sX[nb][(wu * 4 + 0) * 64]);
      async_cp16(g1 + co, &sX[nb][(wu * 4 + 1) * 64]);
      async_cp16(g2 + co, &sX[nb][(wu * 4 + 2) * 64]);
      async_cp16(g3 + co, &sX[nb][(wu * 4 + 3) * 64]);
    }
    // compute phase c: lane = token, 16 float4 of this 64-dim chunk
    const float4* row = &sX[buf][lane * 16];
#pragma unroll
    for (int j = 0; j < 16; ++j) {
      float4 xv = row[j ^ p15];  // physical slot of logical j for token=lane
      int dg = c * 64 + j * 4;
      float4 u0 = *reinterpret_cast<const float4*>(Pq + (size_t)(dg + 0) * 8 + qb);
      float4 u1 = *reinterpret_cast<const float4*>(Pq + (size_t)(dg + 1) * 8 + qb);
      float4 u2 = *reinterpret_cast<const float4*>(Pq + (size_t)(dg + 2) * 8 + qb);
      float4 u3 = *reinterpret_cast<const float4*>(Pq + (size_t)(dg + 3) * 8 + qb);
      a0 += xv.x * u0.x + xv.y * u1.x + xv.z * u2.x + xv.w * u3.x;
      a1 += xv.x * u0.y + xv.y * u1.y + xv.z * u2.y + xv.w * u3.y;
      a2 += xv.x * u0.z + xv.y * u1.z + xv.z * u2.z + xv.w * u3.z;
      a3 += xv.x * u0.w + xv.y * u1.w + xv.z * u2.w + xv.w * u3.w;
    }
    __syncthreads();  // drains next-phase DMA (issued before compute) + RAW/WAR fence
    buf ^= 1;
  }

  float4 o; o.x = a0; o.y = a1; o.z = a2; o.w = a3;
  *reinterpret_cast<float4*>(dots + (size_t)(t0 + lane) * 16 + wu * 4) = o;
}

// --- K2a: top-2 select + renorm weights + per-block expert histograms ---
__global__ void k_top2(const float* __restrict__ dots, const float* __restrict__ beta,
                       float4* __restrict__ wd, int* __restrict__ epk,
                       int* __restrict__ hist) {
  __shared__ int c0[8], c1[8];
  int tid = threadIdx.x;
  if (tid < 8) { c0[tid] = 0; c1[tid] = 0; }
  __syncthreads();
  int t = blockIdx.x * 256 + tid;
  const float* p = dots + (size_t)t * 16;
  float l[8], dv[8];
#pragma unroll
  for (int e = 0; e < 8; ++e) { l[e] = p[e]; dv[e] = p[8 + e]; }
  int e1 = 0; float v1 = l[0];
#pragma unroll
  for (int e = 1; e < 8; ++e) if (l[e] > v1) { v1 = l[e]; e1 = e; }  // ties -> low idx
  int e2 = 0; float v2 = -3.4e38f;
#pragma unroll
  for (int e = 0; e < 8; ++e) if (e != e1 && l[e] > v2) { v2 = l[e]; e2 = e; }
  float wexp = expf(v2 - v1);           // g2/g1 after softmax; renorm over top-2
  float w1 = 1.f / (1.f + wexp);
  float w2 = wexp * w1;
  float d1 = 0.f, d2 = 0.f;
#pragma unroll
  for (int e = 0; e < 8; ++e) {
    d1 = (e == e1) ? dv[e] : d1;
    d2 = (e == e2) ? dv[e] : d2;
  }
  float4 o; o.x = w1; o.y = w2; o.z = d1 + beta[e1]; o.w = d2 + beta[e2];
  wd[t] = o;
  epk[t] = e1 | (e2 << 8);
  atomicAdd(&c0[e1], 1);
  atomicAdd(&c1[e2], 1);
  __syncthreads();
  if (tid < 8) {
    hist[blockIdx.x * 8 + tid] = c0[tid];
    hist[(256 + blockIdx.x) * 8 + tid] = c1[tid];
  }
}

// --- K2b: exclusive scan of 512 block-histograms (k-major order), per expert ---
__global__ void k_scan(const int* __restrict__ hist, int* __restrict__ off) {
  __shared__ int sH[4096];
  __shared__ int sT[256];
  int tid = threadIdx.x;
  for (int i = tid; i < 4096; i += 256) sH[i] = hist[i];
  __syncthreads();
  int e = tid & 7, g = tid >> 3;  // g < 32, each scans 16 rows
  int run = 0;
  for (int i = g * 16; i < g * 16 + 16; ++i) {
    int cv = sH[i * 8 + e]; sH[i * 8 + e] = run; run += cv;
  }
  sT[g * 8 + e] = run;
  __syncthreads();
  if (tid < 8) {
    int run2 = 0;
    for (int g2 = 0; g2 < 32; ++g2) {
      int cv = sT[g2 * 8 + tid]; sT[g2 * 8 + tid] = run2; run2 += cv;
    }
  }
  __syncthreads();
  int add = sT[g * 8 + e];
  for (int i = g * 16; i < g * 16 + 16; ++i) sH[i * 8 + e] += add;
  __syncthreads();
  for (int i = tid; i < 4096; i += 256) off[i] = sH[i];
}

// --- K2c: stable intra-block ranks via ballots -> pos -> keep -> s[t] ---
__global__ void k_keep(const int* __restrict__ epk, const float4* __restrict__ wd,
                       const int* __restrict__ off, float* __restrict__ s) {
  __shared__ int sC0[32], sC1[32];
  int tid = threadIdx.x, lane = tid & 63, w = tid >> 6;
  int t = blockIdx.x * 256 + tid;
  int ep = epk[t]; int e1 = ep & 255, e2 = ep >> 8;
  unsigned long long lt = (1ull << lane) - 1ull;
  int wr0 = 0, wr1 = 0;
#pragma unroll
  for (int e = 0; e < 8; ++e) {
    unsigned long long m0 = __ballot(e1 == e);
    unsigned long long m1 = __ballot(e2 == e);
    if (e == e1) wr0 = __popcll(m0 & lt);
    if (e == e2) wr1 = __popcll(m1 & lt);
    if (lane == 0) { sC0[w * 8 + e] = __popcll(m0); sC1[w * 8 + e] = __popcll(m1); }
  }
  __syncthreads();
  int woff0 = 0, woff1 = 0;
  for (int wp = 0; wp < 4; ++wp) {
    if (wp < w) { woff0 += sC0[wp * 8 + e1]; woff1 += sC1[wp * 8 + e2]; }
  }
  int b = blockIdx.x;
  int pos0 = off[b * 8 + e1] + woff0 + wr0;
  int pos1 = off[(256 + b) * 8 + e2] + woff1 + wr1;
  float4 v = wd[t];
  float sv = 0.f;
  if (pos0 < CAP) sv += v.x * v.z;
  if (pos1 < CAP) sv += v.y * v.w;
  s[t] = sv;
}

// --- K3: per-row (B=8 rows of N=8192) log_softmax ---
__global__ __launch_bounds__(1024) void k_lsm(const float* __restrict__ s,
                                              float* __restrict__ out) {
  __shared__ float sRa[16], sRb[16];
  int tid = threadIdx.x, lane = tid & 63, w = tid >> 6;
  size_t base = (size_t)blockIdx.x * 8192;
  float v[8];
#pragma unroll
  for (int j = 0; j < 8; ++j) v[j] = s[base + tid + j * 1024];
  float mx = v[0];
#pragma unroll
  for (int j = 1; j < 8; ++j) mx = fmaxf(mx, v[j]);
#pragma unroll
  for (int m = 1; m < 64; m <<= 1) mx = fmaxf(mx, __shfl_xor(mx, m, 64));
  if (lane == 0) sRa[w] = mx;
  __syncthreads();
#pragma unroll
  for (int i = 0; i < 16; ++i) mx = fmaxf(mx, sRa[i]);
  float sum = 0.f;
#pragma unroll
  for (int j = 0; j < 8; ++j) sum += expf(v[j] - mx);
#pragma unroll
  for (int m = 1; m < 64; m <<= 1) sum += __shfl_xor(sum, m, 64);
  if (lane == 0) sRb[w] = sum;
  __syncthreads();
  float tot = 0.f;
#pragma unroll
  for (int i = 0; i < 16; ++i) tot += sRb[i];
  float lse = logf(tot);
#pragma unroll
  for (int j = 0; j < 8; ++j) out[base + tid + j * 1024] = v[j] - mx - lse;
}

extern "C" void kernel_launch(void* const* d_in, const int* in_sizes, int n_in,
                              void* d_out, int out_size, void* d_ws, size_t ws_size,
                              hipStream_t stream) {
  const float* x  = (const float*)d_in[0];
  const float* Wg = (const float*)d_in[1];
  const float* W1 = (const float*)d_in[2];
  const float* b1 = (const float*)d_in[3];
  const float* W2 = (const float*)d_in[4];
  const float* b2 = (const float*)d_in[5];
  float* out = (float*)d_out;
  char* ws = (char*)d_ws;

  float*  w2s  = (float*)(ws);                          // 16 KB
  float*  vT   = (float*)(ws + (16u << 10));            // 16 KB
  float*  beta = (float*)(ws + (32u << 10));            // 32 B (padded)
  float*  dots = (float*)(ws + (64u << 10));            // 4 MB
  char*   p1   = ws + (64u << 10) + (4u << 20);
  float4* wd   = (float4*)(p1);                         // 1 MB
  int*    epk  = (int*)(p1 + (1u << 20));               // 256 KB
  int*    hist = (int*)(p1 + (1u << 20) + (256u << 10));// 16 KB
  int*    offa = (int*)(p1 + (1u << 20) + (272u << 10));// 16 KB
  float*  s    = (float*)(p1 + (1u << 20) + (288u << 10)); // 256 KB

  hipLaunchKernelGGL(k_w2s,    dim3(1024), dim3(256),  0, stream, W2, w2s);
  hipLaunchKernelGGL(k_v_beta, dim3(1025), dim3(256),  0, stream, W1, b1, b2, w2s, vT, beta);
  hipLaunchKernelGGL(k_dots,   dim3(1024), dim3(256),  0, stream, x, Wg, vT, dots);
  hipLaunchKernelGGL(k_top2,   dim3(256),  dim3(256),  0, stream, dots, beta, wd, epk, hist);
  hipLaunchKernelGGL(k_scan,   dim3(1),    dim3(256),  0, stream, hist, offa);
  hipLaunchKernelGGL(k_keep,   dim3(256),  dim3(256),  0, stream, epk, wd, offa, s);
  hipLaunchKernelGGL(k_lsm,    dim3(8),    dim3(1024), 0, stream, s, out);
}